// Round 1
// baseline (293.273 us; speedup 1.0000x reference)
//
#include <hip/hip_runtime.h>

// Volume renderer: alpha-compositing over 192 samples per ray.
// One 64-lane wave per ray; lane l owns samples {l, 64+l, 128+l} (strided ->
// every global load/store is perfectly coalesced). Exclusive cumprod of the
// survival probabilities is 3 chained wave-wide shuffle scans with a scalar
// carry. No LDS needed.

#define NRAYS 65536
#define L 192
#define BORDER_W 1e10f
#define EPS_F 1e-10f

__global__ __launch_bounds__(256) void vol_render_kernel(
    const float* __restrict__ depth,   // [N, 192]
    const float* __restrict__ rgb,     // [N, 192, 3]
    const float* __restrict__ sigma,   // [N, 192]
    float* __restrict__ out)           // color N*3 | depth N | acc N | weights N*192
{
    const int lane = threadIdx.x & 63;
    const int wave = threadIdx.x >> 6;
    const int ray  = blockIdx.x * (blockDim.x >> 6) + wave;
    if (ray >= NRAYS) return;

    const float* dptr = depth + (size_t)ray * L;
    const float* sptr = sigma + (size_t)ray * L;
    const float* rptr = rgb   + (size_t)ray * (L * 3);
    float* wptr = out + (size_t)NRAYS * 5 + (size_t)ray * L;

    // Coalesced loads: lane l reads element c*64 + l.
    float d[3], s[3];
#pragma unroll
    for (int c = 0; c < 3; ++c) {
        d[c] = dptr[c * 64 + lane];
        s[c] = sptr[c * 64 + lane];
    }

    // next-sample depth via register shuffles (no extra loads)
    float nx[3];
#pragma unroll
    for (int c = 0; c < 3; ++c) {
        float down = __shfl_down(d[c], 1, 64);
        float first_next = (c < 2) ? __shfl(d[c + 1], 0, 64) : 0.0f;
        nx[c] = (lane == 63) ? first_next : down;
    }

    float carry = 1.0f;   // running transmittance across chunks (wave-uniform)
    float col0 = 0.f, col1 = 0.f, col2 = 0.f, dep = 0.f, acc = 0.f;

#pragma unroll
    for (int c = 0; c < 3; ++c) {
        const int idx = c * 64 + lane;
        float delta = (idx == L - 1) ? BORDER_W : (nx[c] - d[c]);
        float sg = s[c] > 0.0f ? s[c] : 0.0f;            // relu(sigma)
        float e = __expf(-sg * delta);                    // exp(-relu(sigma)*delta)
        float alpha = 1.0f - e;
        float surv  = e + EPS_F;                          // 1 - alpha + eps

        // inclusive product scan across the wave (Hillis-Steele, 6 steps)
        float p = surv;
#pragma unroll
        for (int off = 1; off < 64; off <<= 1) {
            float t = __shfl_up(p, off, 64);
            if (lane >= off) p *= t;
        }
        // exclusive scan value
        float excl = __shfl_up(p, 1, 64);
        if (lane == 0) excl = 1.0f;

        float T = carry * excl;                           // transmittance T_i
        float w = alpha * T;

        wptr[idx] = w;                                    // coalesced weight store

        // rgb: lane reads 12 contiguous bytes; wave covers a contiguous 768B span
        float r0 = rptr[idx * 3 + 0];
        float r1 = rptr[idx * 3 + 1];
        float r2 = rptr[idx * 3 + 2];
        col0 += w / (1.0f + __expf(-r0));                 // sigmoid(rgb) * w
        col1 += w / (1.0f + __expf(-r1));
        col2 += w / (1.0f + __expf(-r2));
        dep  += w * d[c];
        acc  += w;

        carry *= __shfl(p, 63, 64);                       // chunk total product
    }

    // wave-wide reduction of the 5 partial sums
#pragma unroll
    for (int off = 32; off >= 1; off >>= 1) {
        col0 += __shfl_down(col0, off, 64);
        col1 += __shfl_down(col1, off, 64);
        col2 += __shfl_down(col2, off, 64);
        dep  += __shfl_down(dep,  off, 64);
        acc  += __shfl_down(acc,  off, 64);
    }
    if (lane == 0) {
        out[(size_t)ray * 3 + 0] = col0;
        out[(size_t)ray * 3 + 1] = col1;
        out[(size_t)ray * 3 + 2] = col2;
        out[(size_t)NRAYS * 3 + ray] = dep;
        out[(size_t)NRAYS * 4 + ray] = acc;
    }
}

extern "C" void kernel_launch(void* const* d_in, const int* in_sizes, int n_in,
                              void* d_out, int out_size, void* d_ws, size_t ws_size,
                              hipStream_t stream) {
    const float* depth = (const float*)d_in[0];
    const float* rgb   = (const float*)d_in[1];
    const float* sigma = (const float*)d_in[2];
    float* out = (float*)d_out;

    // 4 waves (rays) per 256-thread block
    const int rays_per_block = 4;
    dim3 grid(NRAYS / rays_per_block);
    dim3 block(256);
    vol_render_kernel<<<grid, block, 0, stream>>>(depth, rgb, sigma, out);
}

// Round 2
// 291.805 us; speedup vs baseline: 1.0050x; 1.0050x over previous
//
#include <hip/hip_runtime.h>

// Volume renderer: alpha-compositing over 192 samples per ray.
// One 64-lane wave per ray; lane l owns 3 CONTIGUOUS samples {3l, 3l+1, 3l+2}.
// Each load instruction still covers a contiguous wave-wide span (coalesced).
// The exclusive cumprod = 2 in-lane muls -> ONE 6-step wave product scan ->
// in-lane exclusive products. Sigmoid via v_rcp_f32 (1 instr, ~1 ulp).

#define NRAYS 65536
#define L 192
#define BORDER_W 1e10f
#define EPS_F 1e-10f

__device__ __forceinline__ float fast_sigmoid(float x) {
    return __builtin_amdgcn_rcpf(1.0f + __expf(-x));
}

__global__ __launch_bounds__(256) void vol_render_kernel(
    const float* __restrict__ depth,   // [N, 192]
    const float* __restrict__ rgb,     // [N, 192, 3]
    const float* __restrict__ sigma,   // [N, 192]
    float* __restrict__ out)           // color N*3 | depth N | acc N | weights N*192
{
    const int lane = threadIdx.x & 63;
    const int wave = threadIdx.x >> 6;
    const int ray  = blockIdx.x * (blockDim.x >> 6) + wave;
    if (ray >= NRAYS) return;

    const size_t sbase = (size_t)ray * L + lane * 3;
    // lane l: 3 contiguous samples (wave spans contiguous 768 B per array)
    float d0 = depth[sbase], d1 = depth[sbase + 1], d2 = depth[sbase + 2];
    float s0 = sigma[sbase], s1 = sigma[sbase + 1], s2 = sigma[sbase + 2];

    // deltas: only the chunk boundary needs a shuffle
    float dnext = __shfl_down(d0, 1, 64);            // next lane's first depth
    float delta0 = d1 - d0;
    float delta1 = d2 - d1;
    float delta2 = (lane == 63) ? BORDER_W : (dnext - d2);  // sample 191 = border

    float e0 = __expf(-(s0 > 0.f ? s0 : 0.f) * delta0);
    float e1 = __expf(-(s1 > 0.f ? s1 : 0.f) * delta1);
    float e2 = __expf(-(s2 > 0.f ? s2 : 0.f) * delta2);
    float surv0 = e0 + EPS_F, surv1 = e1 + EPS_F, surv2 = e2 + EPS_F;

    // in-lane prefix products
    float p01  = surv0 * surv1;
    float p012 = p01 * surv2;

    // wave-wide inclusive product scan of per-lane totals (6 steps)
    float p = p012;
#pragma unroll
    for (int off = 1; off < 64; off <<= 1) {
        float t = __shfl_up(p, off, 64);
        if (lane >= off) p *= t;
    }
    float excl = __shfl_up(p, 1, 64);                // exclusive
    if (lane == 0) excl = 1.0f;

    // transmittance & weights for the 3 owned samples
    float T0 = excl;
    float T1 = excl * surv0;
    float T2 = excl * p01;
    float w0 = (1.0f - e0) * T0;
    float w1 = (1.0f - e1) * T1;
    float w2 = (1.0f - e2) * T2;

    // coalesced weight store (wave covers contiguous 768 B)
    float* wptr = out + (size_t)NRAYS * 5 + sbase;
    wptr[0] = w0; wptr[1] = w1; wptr[2] = w2;

    // rgb: lane reads 9 contiguous floats (wave spans contiguous 2304 B)
    const float* rptr = rgb + (size_t)ray * (L * 3) + lane * 9;
    float col0 = w0 * fast_sigmoid(rptr[0]) + w1 * fast_sigmoid(rptr[3]) + w2 * fast_sigmoid(rptr[6]);
    float col1 = w0 * fast_sigmoid(rptr[1]) + w1 * fast_sigmoid(rptr[4]) + w2 * fast_sigmoid(rptr[7]);
    float col2 = w0 * fast_sigmoid(rptr[2]) + w1 * fast_sigmoid(rptr[5]) + w2 * fast_sigmoid(rptr[8]);
    float dep  = w0 * d0 + w1 * d1 + w2 * d2;
    float acc  = w0 + w1 + w2;

    // wave-wide reduction of the 5 partial sums
#pragma unroll
    for (int off = 32; off >= 1; off >>= 1) {
        col0 += __shfl_down(col0, off, 64);
        col1 += __shfl_down(col1, off, 64);
        col2 += __shfl_down(col2, off, 64);
        dep  += __shfl_down(dep,  off, 64);
        acc  += __shfl_down(acc,  off, 64);
    }
    if (lane == 0) {
        out[(size_t)ray * 3 + 0] = col0;
        out[(size_t)ray * 3 + 1] = col1;
        out[(size_t)ray * 3 + 2] = col2;
        out[(size_t)NRAYS * 3 + ray] = dep;
        out[(size_t)NRAYS * 4 + ray] = acc;
    }
}

extern "C" void kernel_launch(void* const* d_in, const int* in_sizes, int n_in,
                              void* d_out, int out_size, void* d_ws, size_t ws_size,
                              hipStream_t stream) {
    const float* depth = (const float*)d_in[0];
    const float* rgb   = (const float*)d_in[1];
    const float* sigma = (const float*)d_in[2];
    float* out = (float*)d_out;

    // 4 waves (rays) per 256-thread block
    const int rays_per_block = 4;
    dim3 grid(NRAYS / rays_per_block);
    dim3 block(256);
    vol_render_kernel<<<grid, block, 0, stream>>>(depth, rgb, sigma, out);
}